// Round 5
// baseline (995.682 us; speedup 1.0000x reference)
//
#include <hip/hip_runtime.h>

// Problem constants
#define CIN   256
#define COUT  384
#define HH    56
#define WW    56
#define HO    54
#define NB    16
#define NPIX  (NB*HO*HO)   // 46656
#define KK    (CIN*9)      // 2304
#define XCH   (HH*WW)      // 3136
#define XIMG  (CIN*HH*WW)  // 802816

#define BM 128
#define BN 128
#define NCHUNK (KK/32)     // 72 chunks of K=32
#define KGRP   (KK/8)      // 288 k-groups of 8
#define WPLANE (KGRP*COUT*8)   // 884736 ushorts per split plane

// ws layout: wg bf16 splits at 0 (5.31MB); offg at 6MiB (9KB); y[COUT][NPIX] fp32 at 8MiB (71.7MB)
#define WS_OFF_OFF (6u << 20)
#define WS_Y_OFF   (8u << 20)

typedef __bf16  bf16x8 __attribute__((ext_vector_type(8)));
typedef float   f32x16 __attribute__((ext_vector_type(16)));
typedef ushort  us8    __attribute__((ext_vector_type(8)));

__device__ __forceinline__ ushort rne_bf16(float f) {
    unsigned u = __float_as_uint(f);
    return (ushort)((u + 0x7FFFu + ((u >> 16) & 1u)) >> 16);
}
__device__ __forceinline__ void split3(float v, ushort& h1, ushort& h2, ushort& h3) {
    h1 = rne_bf16(v);
    float r1 = v - __uint_as_float((unsigned)h1 << 16);   // exact
    h2 = rne_bf16(r1);
    float r2 = r1 - __uint_as_float((unsigned)h2 << 16);  // exact
    h3 = rne_bf16(r2);
}

// W split + retile: wg[s][kgrp][cout][kk8] bf16 — 16B chunk = one (kgrp,cout) run
__global__ __launch_bounds__(256) void wsplit(const float* __restrict__ w,
                                              ushort* __restrict__ wg) {
    int idx = blockIdx.x * 256 + threadIdx.x;     // KK*COUT, k fastest -> coalesced read
    int cout = idx / KK, k = idx - cout * KK;
    ushort h1, h2, h3;
    split3(w[idx], h1, h2, h3);
    int base = ((k >> 3) * COUT + cout) * 8 + (k & 7);
    wg[base]              = h1;
    wg[WPLANE + base]     = h2;
    wg[2 * WPLANE + base] = h3;
}

__global__ __launch_bounds__(256) void offk_init(int* __restrict__ offg) {
    int k = blockIdx.x * 256 + threadIdx.x;
    if (k < KK) {
        int cin = k / 9, r = k - cin * 9;
        int dy = r / 3, dx = r - dy * 3;
        offg[k] = cin * XCH + dy * WW + dx;
    }
}

__global__ __launch_bounds__(256, 3) void conv_mfma(const float* __restrict__ x,
                                                    const ushort* __restrict__ wg,
                                                    const int* __restrict__ offg,
                                                    float* __restrict__ y) {
    // LDS: fragment-native layout [split][kgroup8][row][kk8]; 48KB total -> 3 blocks/CU
    __shared__ __align__(16) ushort As[3][4][128][8];   // 24 KB
    __shared__ __align__(16) ushort Bs[3][4][128][8];   // 24 KB

    const int tid = threadIdx.x;
    const int c0 = blockIdx.y * BM;   // cout tile base
    const int p0 = blockIdx.x * BN;   // pixel tile base

    // B staging: thread owns pixel nb, k-groups gb0 and gb0+2
    const int nb  = tid & 127;
    const int gb0 = tid >> 7;          // 0/1
    int pbase;
    {
        int p = p0 + nb; if (p >= NPIX) p = NPIX - 1;
        int b = p / 2916, rem = p - b * 2916;
        int oy = rem / 54, ox = rem - oy * 54;
        pbase = b * XIMG + oy * WW + ox;
    }

    // wave geometry: 4 waves -> 2x2 grid of 64x64 tiles; 32x32 MFMA frags
    const int lane = tid & 63;
    const int wv = tid >> 6;
    const int wr = wv >> 1, wc = wv & 1;
    const int l31 = lane & 31, lg = lane >> 5;
    const int mrow = wr * 64 + l31;
    const int ncol = wc * 64 + l31;

    f32x16 acc[2][2];
#pragma unroll
    for (int i = 0; i < 2; ++i)
#pragma unroll
        for (int j = 0; j < 2; ++j) acc[i][j] = (f32x16)0.f;

    float4 aPre[6];
    float  bPre[2][8];
    us8    bSpl[2][3];

    auto PREFETCH = [&](int c) {
        // A: 6 x 16B chunks per thread (flat = s*512 + g*128 + m), fully coalesced
#pragma unroll
        for (int r = 0; r < 6; ++r) {
            int flat = r * 256 + tid;
            int s = flat >> 9;
            int g = (flat >> 7) & 3;
            int m = flat & 127;
            aPre[r] = *(const float4*)(wg + ((s * KGRP + (c * 4 + g)) * COUT + (c0 + m)) * 8);
        }
        // B: 2 tasks x 8 pixel-coalesced fp32 loads; k->x offsets via wave-uniform int4
#pragma unroll
        for (int t = 0; t < 2; ++t) {
            int kb = c * 32 + (gb0 + 2 * t) * 8;
            int4 o0 = *(const int4*)(offg + kb);
            int4 o1 = *(const int4*)(offg + kb + 4);
            bPre[t][0] = x[pbase + o0.x];
            bPre[t][1] = x[pbase + o0.y];
            bPre[t][2] = x[pbase + o0.z];
            bPre[t][3] = x[pbase + o0.w];
            bPre[t][4] = x[pbase + o1.x];
            bPre[t][5] = x[pbase + o1.y];
            bPre[t][6] = x[pbase + o1.z];
            bPre[t][7] = x[pbase + o1.w];
        }
    };

    auto SPLITB = [&]() {
#pragma unroll
        for (int t = 0; t < 2; ++t) {
            us8 h1v, h2v, h3v;
#pragma unroll
            for (int kk = 0; kk < 8; ++kk) {
                ushort a, b, c2;
                split3(bPre[t][kk], a, b, c2);
                h1v[kk] = a; h2v[kk] = b; h3v[kk] = c2;
            }
            bSpl[t][0] = h1v; bSpl[t][1] = h2v; bSpl[t][2] = h3v;
        }
    };

    auto WRITE = [&]() {
#pragma unroll
        for (int r = 0; r < 6; ++r) {
            int flat = r * 256 + tid;
            *(float4*)((ushort*)As + flat * 8) = aPre[r];
        }
#pragma unroll
        for (int t = 0; t < 2; ++t) {
            int g = gb0 + 2 * t;
#pragma unroll
            for (int s = 0; s < 3; ++s)
                *(us8*)&Bs[s][g][nb][0] = bSpl[t][s];
        }
    };

    auto COMPUTE = [&]() {
        // A frags: [split][mi][kstep]; lane row = l31, k = lg*8 + i within kstep*16
        bf16x8 af[3][2][2];
#pragma unroll
        for (int s = 0; s < 3; ++s)
#pragma unroll
            for (int mi = 0; mi < 2; ++mi)
#pragma unroll
                for (int ks = 0; ks < 2; ++ks)
                    af[s][mi][ks] = *(const bf16x8*)&As[s][2 * ks + lg][mrow + mi * 32][0];
#pragma unroll
        for (int sb = 0; sb < 3; ++sb) {
            bf16x8 bf[2][2];
#pragma unroll
            for (int ni = 0; ni < 2; ++ni)
#pragma unroll
                for (int ks = 0; ks < 2; ++ks)
                    bf[ni][ks] = *(const bf16x8*)&Bs[sb][2 * ks + lg][ncol + ni * 32][0];
#pragma unroll
            for (int sa = 0; sa + sb < 3; ++sa)
#pragma unroll
                for (int ks = 0; ks < 2; ++ks)
#pragma unroll
                    for (int mi = 0; mi < 2; ++mi)
#pragma unroll
                        for (int ni = 0; ni < 2; ++ni)
                            acc[mi][ni] = __builtin_amdgcn_mfma_f32_32x32x16_bf16(
                                af[sa][mi][ks], bf[ni][ks], acc[mi][ni], 0, 0, 0);
        }
    };

    PREFETCH(0);
    SPLITB();
    WRITE();
    __syncthreads();

    for (int c = 0; ; ) {
        if (c + 1 < NCHUNK) { PREFETCH(c + 1); SPLITB(); }
        COMPUTE();
        if (++c == NCHUNK) break;
        __syncthreads();
        WRITE();
        __syncthreads();
    }

    // epilogue: y[cout][pixel]; 32x32 C/D map: col=lane&31, row=(reg&3)+8*(reg>>2)+4*(lane>>5)
#pragma unroll
    for (int ni = 0; ni < 2; ++ni) {
        int col = p0 + wc * 64 + ni * 32 + l31;
        if (col < NPIX) {
#pragma unroll
            for (int mi = 0; mi < 2; ++mi) {
                int rb = c0 + wr * 64 + mi * 32 + 4 * lg;
#pragma unroll
                for (int reg = 0; reg < 16; ++reg) {
                    int row = rb + (reg & 3) + 8 * (reg >> 2);
                    y[row * NPIX + col] = acc[mi][ni][reg];
                }
            }
        }
    }
}

__global__ __launch_bounds__(256) void gate(const float* __restrict__ y,
                                            float* __restrict__ out) {
    __shared__ float ys[COUT][33];
    __shared__ float gtab[COUT];
    __shared__ float pmax[8][32];
    __shared__ float mx[32];
    __shared__ int   wcnt[32];
    __shared__ int   wlist[32][4];

    const int tid = threadIdx.x;
    const int tx = tid & 31, ty = tid >> 5;
    const int p0 = blockIdx.x * 32;

    for (int k = tid; k < COUT; k += 256) {
        float d = (float)(k - 191);
        gtab[k] = expf(-d * d * (1.0f / (2.0f * 191.0f * 191.0f)));
    }
    if (ty == 0) wcnt[tx] = 0;

    for (int c = ty; c < COUT; c += 8)
        ys[c][tx] = y[c * NPIX + p0 + tx];
    __syncthreads();

    float m = -3.402823466e+38f;
    for (int c = ty; c < COUT; c += 8) m = fmaxf(m, ys[c][tx]);
    pmax[ty][tx] = m;
    __syncthreads();
    if (ty == 0) {
        float mm = pmax[0][tx];
#pragma unroll
        for (int r = 1; r < 8; ++r) mm = fmaxf(mm, pmax[r][tx]);
        mx[tx] = mm;
    }
    __syncthreads();

    const float mm = mx[tx];
    for (int c = ty; c < COUT; c += 8) {
        if (ys[c][tx] >= mm) {
            int pos = atomicAdd(&wcnt[tx], 1);
            if (pos < 4) wlist[tx][pos] = c;
        }
    }
    __syncthreads();

    const int p   = p0 + tx;
    const int b   = p / 2916;
    const int rem = p - b * 2916;
    const int obase = b * (COUT * 2916) + rem;
    const int L = min(wcnt[tx], 4);
    for (int c = ty; c < COUT; c += 8) {
        float lfb = 0.f;
        for (int i = 0; i < L; ++i) {
            int d = wlist[tx][i] - c + 191;
            if (d >= 0 && d < COUT) lfb += gtab[d];
        }
        lfb = fminf(lfb, 1.0f);
        out[obase + c * 2916] = lfb * ys[c][tx];
    }
}

extern "C" void kernel_launch(void* const* d_in, const int* in_sizes, int n_in,
                              void* d_out, int out_size, void* d_ws, size_t ws_size,
                              hipStream_t stream) {
    const float* x = (const float*)d_in[0];
    const float* w = (const float*)d_in[1];
    float* outp = (float*)d_out;

    ushort* wg   = (ushort*)d_ws;                          // 5.31 MB (3 bf16 planes)
    int*    offg = (int*)((char*)d_ws + WS_OFF_OFF);       // 9 KB
    float*  y    = (float*)((char*)d_ws + WS_Y_OFF);       // 71.7 MB

    wsplit<<<(KK * COUT) / 256, 256, 0, stream>>>(w, wg);
    offk_init<<<(KK + 255) / 256, 256, 0, stream>>>(offg);

    dim3 grid((NPIX + BN - 1) / BN, COUT / BM);            // (365, 3)
    conv_mfma<<<grid, 256, 0, stream>>>(x, wg, offg, y);

    gate<<<NPIX / 32, 256, 0, stream>>>(y, outp);
}

// Round 7
// 892.600 us; speedup vs baseline: 1.1155x; 1.1155x over previous
//
#include <hip/hip_runtime.h>

// Problem constants
#define CIN   256
#define COUT  384
#define HH    56
#define WW    56
#define HO    54
#define NB    16
#define NPIX  (NB*HO*HO)   // 46656
#define KK    (CIN*9)      // 2304
#define XCH   (HH*WW)      // 3136
#define XIMG  (CIN*HH*WW)  // 802816

#define BM 128
#define BN 128
#define NCHUNK (KK/16)     // 144 chunks of K=16
#define KGRP   (KK/8)      // 288 k-octets
#define WPLANE (KGRP*COUT*8)   // 884736 ushorts per split plane

// ws layout: wg bf16 splits at 0 (5.31MB); offg at 6MiB (9KB); y[COUT][NPIX] fp32 at 8MiB (71.7MB)
#define WS_OFF_OFF (6u << 20)
#define WS_Y_OFF   (8u << 20)

typedef __bf16  bf16x8 __attribute__((ext_vector_type(8)));
typedef float   f32x16 __attribute__((ext_vector_type(16)));
typedef ushort  us8    __attribute__((ext_vector_type(8)));

__device__ __forceinline__ ushort rne_bf16(float f) {
    unsigned u = __float_as_uint(f);
    return (ushort)((u + 0x7FFFu + ((u >> 16) & 1u)) >> 16);
}
__device__ __forceinline__ void split3(float v, ushort& h1, ushort& h2, ushort& h3) {
    h1 = rne_bf16(v);
    float r1 = v - __uint_as_float((unsigned)h1 << 16);   // exact
    h2 = rne_bf16(r1);
    float r2 = r1 - __uint_as_float((unsigned)h2 << 16);  // exact
    h3 = rne_bf16(r2);
}

// W split + retile: wg[s][kgrp][cout][kk8] bf16 — 16B chunk = one (kgrp,cout) run
__global__ __launch_bounds__(256) void wsplit(const float* __restrict__ w,
                                              ushort* __restrict__ wg) {
    int idx = blockIdx.x * 256 + threadIdx.x;     // KK*COUT, k fastest -> coalesced read
    int cout = idx / KK, k = idx - cout * KK;
    ushort h1, h2, h3;
    split3(w[idx], h1, h2, h3);
    int base = ((k >> 3) * COUT + cout) * 8 + (k & 7);
    wg[base]              = h1;
    wg[WPLANE + base]     = h2;
    wg[2 * WPLANE + base] = h3;
}

__global__ __launch_bounds__(256) void offk_init(int* __restrict__ offg) {
    int k = blockIdx.x * 256 + threadIdx.x;
    if (k < KK) {
        int cin = k / 9, r = k - cin * 9;
        int dy = r / 3, dx = r - dy * 3;
        offg[k] = cin * XCH + dy * WW + dx;
    }
}

__global__ __launch_bounds__(256, 3) void conv_mfma(const float* __restrict__ x,
                                                    const ushort* __restrict__ wg,
                                                    const int* __restrict__ offg,
                                                    float* __restrict__ y) {
    // Double-buffered, fragment-native: [buf][split][k-octet][row][kk8]; 48KB total
    __shared__ __align__(16) ushort As[2][3][2][128][8];   // 2 x 12 KB
    __shared__ __align__(16) ushort Bs[2][3][2][128][8];   // 2 x 12 KB

    const int tid = threadIdx.x;
    const int c0 = blockIdx.y * BM;   // cout tile base
    const int p0 = blockIdx.x * BN;   // pixel tile base

    // staging role: thread owns row nb (cout for A, pixel for B), k-octet gb
    const int nb = tid & 127;
    const int gb = tid >> 7;           // 0/1 (wave-uniform)
    int pbase;
    {
        int p = p0 + nb; if (p >= NPIX) p = NPIX - 1;
        int b = p / 2916, rem = p - b * 2916;
        int oy = rem / 54, ox = rem - oy * 54;
        pbase = b * XIMG + oy * WW + ox;
    }

    // wave geometry: 4 waves -> 2x2 grid of 64x64 tiles; 32x32x16 MFMA frags
    const int lane = tid & 63;
    const int wv = tid >> 6;
    const int wr = wv >> 1, wc = wv & 1;
    const int l31 = lane & 31, lg = lane >> 5;
    const int arow = wr * 64 + l31;
    const int brow = wc * 64 + l31;

    f32x16 acc[2][2];
#pragma unroll
    for (int i = 0; i < 2; ++i)
#pragma unroll
        for (int j = 0; j < 2; ++j) acc[i][j] = (f32x16)0.f;

    float4 aPre[3];
    float  bPre[8];

    auto PREFETCH = [&](int c) {
        // A: 3 split planes, 16B per plane per thread; kgrp = 2c+gb, cout = c0+nb
        const ushort* wp = wg + ((2 * c + gb) * COUT + c0 + nb) * 8;
#pragma unroll
        for (int r = 0; r < 3; ++r)
            aPre[r] = *(const float4*)(wp + r * WPLANE);
        // B: 8 pixel-coalesced x loads; k -> x offset via wave-uniform int4
        int kb = c * 16 + gb * 8;
        int4 o0 = *(const int4*)(offg + kb);
        int4 o1 = *(const int4*)(offg + kb + 4);
        bPre[0] = x[pbase + o0.x];
        bPre[1] = x[pbase + o0.y];
        bPre[2] = x[pbase + o0.z];
        bPre[3] = x[pbase + o0.w];
        bPre[4] = x[pbase + o1.x];
        bPre[5] = x[pbase + o1.y];
        bPre[6] = x[pbase + o1.z];
        bPre[7] = x[pbase + o1.w];
    };

    auto WRITE = [&](int buf) {
#pragma unroll
        for (int r = 0; r < 3; ++r)
            *(float4*)&As[buf][r][gb][nb][0] = aPre[r];
        us8 h1v, h2v, h3v;
#pragma unroll
        for (int kk = 0; kk < 8; ++kk) {
            ushort a, b, c2;
            split3(bPre[kk], a, b, c2);
            h1v[kk] = a; h2v[kk] = b; h3v[kk] = c2;
        }
        *(us8*)&Bs[buf][0][gb][nb][0] = h1v;
        *(us8*)&Bs[buf][1][gb][nb][0] = h2v;
        *(us8*)&Bs[buf][2][gb][nb][0] = h3v;
    };

    auto COMPUTE = [&](int buf) {
        bf16x8 af[3][2];
#pragma unroll
        for (int s = 0; s < 3; ++s)
#pragma unroll
            for (int mi = 0; mi < 2; ++mi)
                af[s][mi] = *(const bf16x8*)&As[buf][s][lg][arow + mi * 32][0];
#pragma unroll
        for (int sb = 0; sb < 3; ++sb) {
            bf16x8 bf0 = *(const bf16x8*)&Bs[buf][sb][lg][brow][0];
            bf16x8 bf1 = *(const bf16x8*)&Bs[buf][sb][lg][brow + 32][0];
#pragma unroll
            for (int sa = 0; sa + sb < 3; ++sa) {
                acc[0][0] = __builtin_amdgcn_mfma_f32_32x32x16_bf16(af[sa][0], bf0, acc[0][0], 0, 0, 0);
                acc[0][1] = __builtin_amdgcn_mfma_f32_32x32x16_bf16(af[sa][0], bf1, acc[0][1], 0, 0, 0);
                acc[1][0] = __builtin_amdgcn_mfma_f32_32x32x16_bf16(af[sa][1], bf0, acc[1][0], 0, 0, 0);
                acc[1][1] = __builtin_amdgcn_mfma_f32_32x32x16_bf16(af[sa][1], bf1, acc[1][1], 0, 0, 0);
            }
        }
    };

    PREFETCH(0);
    WRITE(0);
    __syncthreads();

    int cur = 0;
    for (int c = 0; ; ) {
        if (c + 1 < NCHUNK) PREFETCH(c + 1);
        COMPUTE(cur);
        if (++c == NCHUNK) break;
        WRITE(cur ^ 1);
        __syncthreads();
        cur ^= 1;
    }

    // epilogue: y[cout][pixel]; 32x32 C/D map: col=lane&31, row=(reg&3)+8*(reg>>2)+4*(lane>>5)
#pragma unroll
    for (int ni = 0; ni < 2; ++ni) {
        int col = p0 + wc * 64 + ni * 32 + l31;
        if (col < NPIX) {
#pragma unroll
            for (int mi = 0; mi < 2; ++mi) {
                int rb = c0 + wr * 64 + mi * 32 + 4 * lg;
#pragma unroll
                for (int reg = 0; reg < 16; ++reg) {
                    int row = rb + (reg & 3) + 8 * (reg >> 2);
                    y[row * NPIX + col] = acc[mi][ni][reg];
                }
            }
        }
    }
}

__global__ __launch_bounds__(256) void gate(const float* __restrict__ y,
                                            float* __restrict__ out) {
    __shared__ float ys[COUT][33];
    __shared__ float gtab[COUT];
    __shared__ float pmax[8][32];
    __shared__ float mx[32];
    __shared__ int   wcnt[32];
    __shared__ int   wlist[32][4];

    const int tid = threadIdx.x;
    const int tx = tid & 31, ty = tid >> 5;
    const int p0 = blockIdx.x * 32;

    for (int k = tid; k < COUT; k += 256) {
        float d = (float)(k - 191);
        gtab[k] = expf(-d * d * (1.0f / (2.0f * 191.0f * 191.0f)));
    }
    if (ty == 0) wcnt[tx] = 0;

    for (int c = ty; c < COUT; c += 8)
        ys[c][tx] = y[c * NPIX + p0 + tx];
    __syncthreads();

    float m = -3.402823466e+38f;
    for (int c = ty; c < COUT; c += 8) m = fmaxf(m, ys[c][tx]);
    pmax[ty][tx] = m;
    __syncthreads();
    if (ty == 0) {
        float mm = pmax[0][tx];
#pragma unroll
        for (int r = 1; r < 8; ++r) mm = fmaxf(mm, pmax[r][tx]);
        mx[tx] = mm;
    }
    __syncthreads();

    const float mm = mx[tx];
    for (int c = ty; c < COUT; c += 8) {
        if (ys[c][tx] >= mm) {
            int pos = atomicAdd(&wcnt[tx], 1);
            if (pos < 4) wlist[tx][pos] = c;
        }
    }
    __syncthreads();

    const int p   = p0 + tx;
    const int b   = p / 2916;
    const int rem = p - b * 2916;
    const int obase = b * (COUT * 2916) + rem;
    const int L = min(wcnt[tx], 4);
    for (int c = ty; c < COUT; c += 8) {
        float lfb = 0.f;
        for (int i = 0; i < L; ++i) {
            int d = wlist[tx][i] - c + 191;
            if (d >= 0 && d < COUT) lfb += gtab[d];
        }
        lfb = fminf(lfb, 1.0f);
        out[obase + c * 2916] = lfb * ys[c][tx];
    }
}

extern "C" void kernel_launch(void* const* d_in, const int* in_sizes, int n_in,
                              void* d_out, int out_size, void* d_ws, size_t ws_size,
                              hipStream_t stream) {
    const float* x = (const float*)d_in[0];
    const float* w = (const float*)d_in[1];
    float* outp = (float*)d_out;

    ushort* wg   = (ushort*)d_ws;                          // 5.31 MB (3 bf16 planes)
    int*    offg = (int*)((char*)d_ws + WS_OFF_OFF);       // 9 KB
    float*  y    = (float*)((char*)d_ws + WS_Y_OFF);       // 71.7 MB

    wsplit<<<(KK * COUT) / 256, 256, 0, stream>>>(w, wg);
    offk_init<<<(KK + 255) / 256, 256, 0, stream>>>(offg);

    dim3 grid((NPIX + BN - 1) / BN, COUT / BM);            // (365, 3)
    conv_mfma<<<grid, 256, 0, stream>>>(x, wg, offg, y);

    gate<<<NPIX / 32, 256, 0, stream>>>(y, outp);
}